// Round 1
// baseline (934.170 us; speedup 1.0000x reference)
//
#include <hip/hip_runtime.h>

#define PLANE_RES 1024
#define PLANE_STRIDE (PLANE_RES * PLANE_RES)  // float2 elements per plane

__global__ __launch_bounds__(256) void triplane_kernel(
    const float* __restrict__ positions,      // (B, 3)
    const float* __restrict__ plane_embedding, // (3, 1024*1024, 2) flat
    float* __restrict__ out,                   // (B, 32)
    int B)
{
    int b = blockIdx.x * blockDim.x + threadIdx.x;
    if (b >= B) return;

    const float x = positions[(size_t)b * 3 + 0];
    const float y = positions[(size_t)b * 3 + 1];
    const float z = positions[(size_t)b * 3 + 2];

    const float scales[4] = {128.0f, 256.0f, 512.0f, 1024.0f};
    const int   facs[4]   = {8, 4, 2, 1};

    const float2* __restrict__ tab = (const float2*)plane_embedding;

    float res[32];

    #pragma unroll
    for (int l = 0; l < 4; ++l) {
        const float s = scales[l] - 1.0f;
        const float px = x * s + 0.5f;
        const float py = y * s + 0.5f;
        const float pz = z * s + 0.5f;
        const int gx = (int)floorf(px);
        const int gy = (int)floorf(py);
        const int gz = (int)floorf(pz);
        const float fx = px - (float)gx;
        const float fy = py - (float)gy;
        const float fz = pz - (float)gz;
        const int fac = facs[l];

        // plane p uses axes (c0[p], c1[p]) = (0,1), (1,2), (2,0)
        const int   g0s[3] = {gx, gy, gz};
        const int   g1s[3] = {gy, gz, gx};
        const float f0s[3] = {fx, fy, fz};
        const float f1s[3] = {fy, fz, fx};

        float acc[3][2];

        #pragma unroll
        for (int p = 0; p < 3; ++p) {
            const int i0a = min(g0s[p] * fac,       PLANE_RES - 1);
            const int i0b = min((g0s[p] + 1) * fac, PLANE_RES - 1);
            const int i1a = min(g1s[p] * fac,       PLANE_RES - 1);
            const int i1b = min((g1s[p] + 1) * fac, PLANE_RES - 1);

            const float2* __restrict__ base = tab + (size_t)p * PLANE_STRIDE;
            const float2 c00 = base[i0a + i1a * PLANE_RES]; // dx=0, dy=0
            const float2 c01 = base[i0a + i1b * PLANE_RES]; // dx=0, dy=1
            const float2 c10 = base[i0b + i1a * PLANE_RES]; // dx=1, dy=0
            const float2 c11 = base[i0b + i1b * PLANE_RES]; // dx=1, dy=1

            const float w0 = f0s[p], w1 = f1s[p];
            // reference accumulation order: dx=0(dy=0,dy=1), dx=1(dy=0,dy=1)
            float a0 = (1.0f - w0) * (1.0f - w1) * c00.x;
            float a1 = (1.0f - w0) * (1.0f - w1) * c00.y;
            a0 += (1.0f - w0) * w1 * c01.x;
            a1 += (1.0f - w0) * w1 * c01.y;
            a0 += w0 * (1.0f - w1) * c10.x;
            a1 += w0 * (1.0f - w1) * c10.y;
            a0 += w0 * w1 * c11.x;
            a1 += w0 * w1 * c11.y;
            acc[p][0] = a0;
            acc[p][1] = a1;
        }

        res[l * 8 + 0] = acc[0][0];
        res[l * 8 + 1] = acc[0][1];
        res[l * 8 + 2] = acc[1][0];
        res[l * 8 + 3] = acc[1][1];
        res[l * 8 + 4] = acc[2][0];
        res[l * 8 + 5] = acc[2][1];
        res[l * 8 + 6] = acc[0][0] * acc[1][0] * acc[2][0];
        res[l * 8 + 7] = acc[0][1] * acc[1][1] * acc[2][1];
    }

    // contiguous 128 B per thread; 8x float4 stores
    float4* __restrict__ o4 = (float4*)(out + (size_t)b * 32);
    #pragma unroll
    for (int j = 0; j < 8; ++j) {
        o4[j] = make_float4(res[j * 4 + 0], res[j * 4 + 1],
                            res[j * 4 + 2], res[j * 4 + 3]);
    }
}

extern "C" void kernel_launch(void* const* d_in, const int* in_sizes, int n_in,
                              void* d_out, int out_size, void* d_ws, size_t ws_size,
                              hipStream_t stream) {
    const float* positions = (const float*)d_in[0];
    const float* plane_embedding = (const float*)d_in[1];
    float* out = (float*)d_out;
    const int B = in_sizes[0] / 3;

    const int block = 256;
    const int grid = (B + block - 1) / block;
    triplane_kernel<<<grid, block, 0, stream>>>(positions, plane_embedding, out, B);
}

// Round 2
// 740.713 us; speedup vs baseline: 1.2612x; 1.2612x over previous
//
#include <hip/hip_runtime.h>

#define PLANE_RES 1024
#define PLANE_STRIDE (PLANE_RES * PLANE_RES)  // float2 elements per plane
#define NBUCKETS 32768                        // 2^15 morton buckets (5 bits/axis)
#define SCAN_THREADS 1024
#define PER_THREAD (NBUCKETS / SCAN_THREADS)  // 32

// ---------------- shared compute: one position -> 32 output floats ----------
__device__ __forceinline__ void encode_one(
    float x, float y, float z, const float2* __restrict__ tab, float* res)
{
    const float scales[4] = {128.0f, 256.0f, 512.0f, 1024.0f};
    const int   facs[4]   = {8, 4, 2, 1};

    #pragma unroll
    for (int l = 0; l < 4; ++l) {
        const float s = scales[l] - 1.0f;
        const float px = x * s + 0.5f;
        const float py = y * s + 0.5f;
        const float pz = z * s + 0.5f;
        const int gx = (int)floorf(px);
        const int gy = (int)floorf(py);
        const int gz = (int)floorf(pz);
        const float fx = px - (float)gx;
        const float fy = py - (float)gy;
        const float fz = pz - (float)gz;
        const int fac = facs[l];

        const int   g0s[3] = {gx, gy, gz};
        const int   g1s[3] = {gy, gz, gx};
        const float f0s[3] = {fx, fy, fz};
        const float f1s[3] = {fy, fz, fx};

        float acc[3][2];

        #pragma unroll
        for (int p = 0; p < 3; ++p) {
            const int i0a = min(g0s[p] * fac,       PLANE_RES - 1);
            const int i0b = min((g0s[p] + 1) * fac, PLANE_RES - 1);
            const int i1a = min(g1s[p] * fac,       PLANE_RES - 1);
            const int i1b = min((g1s[p] + 1) * fac, PLANE_RES - 1);

            const float2* __restrict__ base = tab + (size_t)p * PLANE_STRIDE;
            const float2 c00 = base[i0a + i1a * PLANE_RES];
            const float2 c01 = base[i0a + i1b * PLANE_RES];
            const float2 c10 = base[i0b + i1a * PLANE_RES];
            const float2 c11 = base[i0b + i1b * PLANE_RES];

            const float w0 = f0s[p], w1 = f1s[p];
            float a0 = (1.0f - w0) * (1.0f - w1) * c00.x;
            float a1 = (1.0f - w0) * (1.0f - w1) * c00.y;
            a0 += (1.0f - w0) * w1 * c01.x;
            a1 += (1.0f - w0) * w1 * c01.y;
            a0 += w0 * (1.0f - w1) * c10.x;
            a1 += w0 * (1.0f - w1) * c10.y;
            a0 += w0 * w1 * c11.x;
            a1 += w0 * w1 * c11.y;
            acc[p][0] = a0;
            acc[p][1] = a1;
        }

        res[l * 8 + 0] = acc[0][0];
        res[l * 8 + 1] = acc[0][1];
        res[l * 8 + 2] = acc[1][0];
        res[l * 8 + 3] = acc[1][1];
        res[l * 8 + 4] = acc[2][0];
        res[l * 8 + 5] = acc[2][1];
        res[l * 8 + 6] = acc[0][0] * acc[1][0] * acc[2][0];
        res[l * 8 + 7] = acc[0][1] * acc[1][1] * acc[2][1];
    }
}

// ---------------- morton key: top 5 bits of each axis's level-3 cell --------
__device__ __forceinline__ unsigned part1by2(unsigned v) {
    v &= 0x3ff;
    v = (v | (v << 16)) & 0x030000FFu;
    v = (v | (v << 8))  & 0x0300F00Fu;
    v = (v | (v << 4))  & 0x030C30C3u;
    v = (v | (v << 2))  & 0x09249249u;
    return v;
}

__device__ __forceinline__ unsigned morton_key(float x, float y, float z) {
    int gx = (int)floorf(x * 1023.0f + 0.5f);
    int gy = (int)floorf(y * 1023.0f + 0.5f);
    int gz = (int)floorf(z * 1023.0f + 0.5f);
    unsigned bx = ((unsigned)gx) >> 5;  // [0,31]
    unsigned by = ((unsigned)gy) >> 5;
    unsigned bz = ((unsigned)gz) >> 5;
    return (part1by2(bx) << 2) | (part1by2(by) << 1) | part1by2(bz);  // 15 bits
}

// ---------------- pass 1: histogram --------------------------------------
__global__ __launch_bounds__(256) void hist_kernel(
    const float* __restrict__ positions, unsigned* __restrict__ hist, int B)
{
    int i = blockIdx.x * blockDim.x + threadIdx.x;
    if (i >= B) return;
    const float x = positions[(size_t)i * 3 + 0];
    const float y = positions[(size_t)i * 3 + 1];
    const float z = positions[(size_t)i * 3 + 2];
    atomicAdd(&hist[morton_key(x, y, z)], 1u);
}

// ---------------- pass 2: exclusive scan of 32768 bins, single block -------
__global__ __launch_bounds__(SCAN_THREADS) void scan_kernel(unsigned* __restrict__ hist)
{
    __shared__ unsigned partials[SCAN_THREADS];
    const int t = threadIdx.x;
    unsigned vals[PER_THREAD];
    unsigned sum = 0;
    #pragma unroll
    for (int j = 0; j < PER_THREAD; ++j) {
        vals[j] = hist[t * PER_THREAD + j];
        sum += vals[j];
    }
    partials[t] = sum;
    __syncthreads();
    // Hillis-Steele inclusive scan over 1024 partials
    #pragma unroll
    for (int off = 1; off < SCAN_THREADS; off <<= 1) {
        unsigned u = (t >= off) ? partials[t - off] : 0u;
        __syncthreads();
        partials[t] += u;
        __syncthreads();
    }
    unsigned running = partials[t] - sum;  // exclusive base for this thread
    #pragma unroll
    for (int j = 0; j < PER_THREAD; ++j) {
        unsigned v = vals[j];
        hist[t * PER_THREAD + j] = running;
        running += v;
    }
}

// ---------------- pass 3: scatter positions into morton order --------------
__global__ __launch_bounds__(256) void scatter_kernel(
    const float* __restrict__ positions, unsigned* __restrict__ offs,
    float4* __restrict__ sorted, int B)
{
    int i = blockIdx.x * blockDim.x + threadIdx.x;
    if (i >= B) return;
    const float x = positions[(size_t)i * 3 + 0];
    const float y = positions[(size_t)i * 3 + 1];
    const float z = positions[(size_t)i * 3 + 2];
    unsigned k = morton_key(x, y, z);
    unsigned dst = atomicAdd(&offs[k], 1u);
    sorted[dst] = make_float4(x, y, z, __int_as_float(i));
}

// ---------------- main kernel (sorted order) --------------------------------
__global__ __launch_bounds__(256) void triplane_sorted_kernel(
    const float4* __restrict__ sorted,
    const float* __restrict__ plane_embedding,
    float* __restrict__ out, int B, int swizzle)
{
    int b = blockIdx.x;
    if (swizzle) {
        // give each XCD one contiguous morton octant
        int per = gridDim.x >> 3;
        b = (b & 7) * per + (b >> 3);
    }
    int i = b * blockDim.x + threadIdx.x;
    if (i >= B) return;

    const float4 p = sorted[i];
    const int orig = __float_as_int(p.w);
    const float2* __restrict__ tab = (const float2*)plane_embedding;

    float res[32];
    encode_one(p.x, p.y, p.z, tab, res);

    float4* __restrict__ o4 = (float4*)(out + (size_t)orig * 32);
    #pragma unroll
    for (int j = 0; j < 8; ++j) {
        o4[j] = make_float4(res[j * 4 + 0], res[j * 4 + 1],
                            res[j * 4 + 2], res[j * 4 + 3]);
    }
}

// ---------------- fallback: unsorted (round-1) ------------------------------
__global__ __launch_bounds__(256) void triplane_plain_kernel(
    const float* __restrict__ positions,
    const float* __restrict__ plane_embedding,
    float* __restrict__ out, int B)
{
    int i = blockIdx.x * blockDim.x + threadIdx.x;
    if (i >= B) return;
    const float x = positions[(size_t)i * 3 + 0];
    const float y = positions[(size_t)i * 3 + 1];
    const float z = positions[(size_t)i * 3 + 2];
    const float2* __restrict__ tab = (const float2*)plane_embedding;
    float res[32];
    encode_one(x, y, z, tab, res);
    float4* __restrict__ o4 = (float4*)(out + (size_t)i * 32);
    #pragma unroll
    for (int j = 0; j < 8; ++j) {
        o4[j] = make_float4(res[j * 4 + 0], res[j * 4 + 1],
                            res[j * 4 + 2], res[j * 4 + 3]);
    }
}

extern "C" void kernel_launch(void* const* d_in, const int* in_sizes, int n_in,
                              void* d_out, int out_size, void* d_ws, size_t ws_size,
                              hipStream_t stream) {
    const float* positions = (const float*)d_in[0];
    const float* plane_embedding = (const float*)d_in[1];
    float* out = (float*)d_out;
    const int B = in_sizes[0] / 3;

    const int block = 256;
    const int grid = (B + block - 1) / block;

    // ws layout: [0, 128KB) offsets/hist, [128KB, 128KB + B*16) sorted float4
    const size_t offs_bytes = (size_t)NBUCKETS * sizeof(unsigned);
    const size_t need = offs_bytes + (size_t)B * sizeof(float4);

    if (ws_size < need) {
        triplane_plain_kernel<<<grid, block, 0, stream>>>(positions, plane_embedding, out, B);
        return;
    }

    unsigned* offs = (unsigned*)d_ws;
    float4* sorted = (float4*)((char*)d_ws + offs_bytes);

    hipMemsetAsync(offs, 0, offs_bytes, stream);
    hist_kernel<<<grid, block, 0, stream>>>(positions, offs, B);
    scan_kernel<<<1, SCAN_THREADS, 0, stream>>>(offs);
    scatter_kernel<<<grid, block, 0, stream>>>(positions, offs, sorted, B);

    const int swizzle = (grid % 8 == 0) ? 1 : 0;
    triplane_sorted_kernel<<<grid, block, 0, stream>>>(sorted, plane_embedding, out, B, swizzle);
}